// Round 5
// baseline (115.038 us; speedup 1.0000x reference)
//
#include <hip/hip_runtime.h>

// make_blocks: out[b,p,a,c,:] = concat(seq1M[b, r0+c, :], seq2M[b, c0+a, :], geo[b,p,a,c])
// B=64, L=2048, D=60, P=16, PS=30 -> out [64,16,30,30,121] fp32 (446 MB).
//
// R5: R4 descriptor core + WRITE-STREAM SHAPING.
//   - 256 blocks x 1024 threads; each block sweeps 4 CONSECUTIVE chunks
//     sequentially -> 256 concurrent write streams (was 2048) for DRAM row locality.
//   - XCD-contiguous chunk ranges (bid&7 -> chunks [xcd*128, ...)) so each XCD's
//     source working set (~2.3 MB) stays L2-resident after first touch.
//   - LDS double-buffer + async staging: issue next chunk's global loads BEFORE
//     the current store sweep, ds_write them after (T14 split).

constexpr int B_    = 64;
constexpr int L_    = 2048;
constexpr int D_    = 60;
constexpr int P_    = 16;
constexpr int PS_   = 30;
constexpr int KOUT  = 2 * D_ + 1;          // 121
constexpr int NPAIR = PS_ * PS_;           // 900
constexpr int CHUNK = NPAIR * KOUT;        // 108900 floats per (b,p)
constexpr int ROWF  = PS_ * KOUT;          // 3630
constexpr int AP_F4 = 2 * ROWF / 4;        // 1815 float4 per a-pair stripe
constexpr int NAP   = PS_ / 2;             // 15 stripes per chunk

constexpr int NT  = 1024;
constexpr int NS  = 2;                     // ceil(1815/1024) f4 slots per thread
constexpr int CPB = 4;                     // chunks per block
constexpr int NBLK = (B_ * P_) / CPB;      // 256
constexpr int XCDS = 8;
constexpr int CH_PER_XCD = (B_ * P_) / XCDS;  // 128

constexpr int RPAD  = 64;
constexpr int CBASE = PS_ * RPAD;          // 1920
constexpr int GBASE = 2 * CBASE;           // 3840
constexpr int LDSF  = GBASE + PS_ * 32;    // 4800 floats per buffer (19.2 KB)

constexpr int NSRC = 2 * PS_ * D_ + NPAIR; // 4500 staged floats per chunk
constexpr int NSTG = (NSRC + NT - 1) / NT; // 5 per thread

__device__ __forceinline__ int perm60(int k) { return (k & 3) * 15 + (k >> 2); }

__device__ __forceinline__ int stage_lds_off(int i) {
    if (i < PS_ * D_)     { int c = i / D_, k = i - c * D_; return c * RPAD + perm60(k); }
    if (i < 2 * PS_ * D_) { int j = i - PS_ * D_; int c = j / D_, k = j - c * D_;
                            return CBASE + c * RPAD + perm60(k); }
    int j = i - 2 * PS_ * D_; int a = j / PS_, c = j - a * PS_;
    return GBASE + a * 32 + c;
}

__device__ __forceinline__ void issue_loads(const float* __restrict__ seq1,
                                            const float* __restrict__ seq2,
                                            const float* __restrict__ geo,
                                            int bp, int r0, int c0, int tid,
                                            float stg[NSTG]) {
    const float* s1 = seq1 + ((size_t)(bp / P_) * L_ + r0) * D_;
    const float* s2 = seq2 + ((size_t)(bp / P_) * L_ + c0) * D_;
    const float* gg = geo  + (size_t)bp * NPAIR;
#pragma unroll
    for (int n = 0; n < NSTG; ++n) {
        const int i = tid + n * NT;
        if (i < NSRC) {
            float v;
            if (i < PS_ * D_)          v = s1[i];
            else if (i < 2 * PS_ * D_) v = s2[i - PS_ * D_];
            else                       v = gg[i - 2 * PS_ * D_];
            stg[n] = v;
        }
    }
}

__device__ __forceinline__ void write_lds(float* __restrict__ buf, const float stg[NSTG],
                                          const int loff[NSTG], int tid) {
#pragma unroll
    for (int n = 0; n < NSTG; ++n) {
        if (tid + n * NT < NSRC) buf[loff[n]] = stg[n];
    }
}

__device__ __forceinline__ void sweep(const char* __restrict__ shb,
                                      const int off0[NS][4], const int strb[NS][4],
                                      const bool valid[NS],
                                      float4* __restrict__ outf4, int tid) {
    int offb[NS][4];
#pragma unroll
    for (int s = 0; s < NS; ++s)
#pragma unroll
        for (int j = 0; j < 4; ++j) offb[s][j] = off0[s][j];

    for (int ap = 0; ap < NAP; ++ap) {
#pragma unroll
        for (int s = 0; s < NS; ++s) {
            if (valid[s]) {
                float4 v;
                v.x = *reinterpret_cast<const float*>(shb + offb[s][0]);
                v.y = *reinterpret_cast<const float*>(shb + offb[s][1]);
                v.z = *reinterpret_cast<const float*>(shb + offb[s][2]);
                v.w = *reinterpret_cast<const float*>(shb + offb[s][3]);
                outf4[(size_t)ap * AP_F4 + tid + s * NT] = v;
            }
#pragma unroll
            for (int j = 0; j < 4; ++j) offb[s][j] += strb[s][j];
        }
    }
}

__global__ __launch_bounds__(NT, 1) void make_blocks_38860864094557_kernel(
    const float* __restrict__ seq1, const float* __restrict__ seq2,
    const float* __restrict__ geo,  const int* __restrict__ patches,
    float* __restrict__ out)
{
    __shared__ float sh[2][LDSF];   // 38.4 KB

    const int tid = threadIdx.x;
    const int bid = blockIdx.x;
    // XCD-contiguous mapping: blocks dispatch round-robin over 8 XCDs; give
    // XCD x the contiguous chunk range [x*128, (x+1)*128).
    const int xcd = bid & (XCDS - 1);
    const int sub = bid >> 3;
    const int bp0 = xcd * CH_PER_XCD + sub * CPB;

    int r0s[CPB], c0s[CPB];
#pragma unroll
    for (int t = 0; t < CPB; ++t) {
        r0s[t] = patches[(bp0 + t) * 2 + 0];
        c0s[t] = patches[(bp0 + t) * 2 + 1];
    }

    // Staging LDS offsets (chunk-independent).
    int loff[NSTG];
#pragma unroll
    for (int n = 0; n < NSTG; ++n) {
        const int i = tid + n * NT;
        loff[n] = (i < NSRC) ? stage_lds_off(i) : 0;
    }

    // Per-thread gather descriptors (byte offsets into a buffer + per-stripe strides).
    int off0[NS][4], strb[NS][4];
    bool valid[NS];
#pragma unroll
    for (int s = 0; s < NS; ++s) {
        const int u4 = tid + s * NT;
        valid[s] = (u4 < AP_F4);
        const int u4c = valid[s] ? u4 : (AP_F4 - 1);
#pragma unroll
        for (int j = 0; j < 4; ++j) {
            const int u  = 4 * u4c + j;
            const int ah = (u >= ROWF) ? 1 : 0;
            const int r  = u - ah * ROWF;
            const int c  = r / KOUT;
            const int k  = r - c * KOUT;
            int off, st;
            if (k < D_)          { off = c * RPAD + perm60(k);                st = 0;        }
            else if (k < 2*D_)   { off = CBASE + ah * RPAD + perm60(k - D_);  st = 2 * RPAD; }
            else                 { off = GBASE + ah * 32 + c;                 st = 2 * 32;   }
            off0[s][j] = off * 4;
            strb[s][j] = st * 4;
        }
    }

    float4* o0 = reinterpret_cast<float4*>(out + (size_t)(bp0 + 0) * CHUNK);
    float4* o1 = reinterpret_cast<float4*>(out + (size_t)(bp0 + 1) * CHUNK);
    float4* o2 = reinterpret_cast<float4*>(out + (size_t)(bp0 + 2) * CHUNK);
    float4* o3 = reinterpret_cast<float4*>(out + (size_t)(bp0 + 3) * CHUNK);

    float stg[NSTG];

    // Prologue: stage chunk 0.
    issue_loads(seq1, seq2, geo, bp0 + 0, r0s[0], c0s[0], tid, stg);
    write_lds(sh[0], stg, loff, tid);
    __syncthreads();

    // t=0: prefetch 1, sweep 0 (sh[0]), write 1 -> sh[1]
    issue_loads(seq1, seq2, geo, bp0 + 1, r0s[1], c0s[1], tid, stg);
    sweep(reinterpret_cast<const char*>(sh[0]), off0, strb, valid, o0, tid);
    write_lds(sh[1], stg, loff, tid);
    __syncthreads();

    // t=1: prefetch 2, sweep 1 (sh[1]), write 2 -> sh[0]
    issue_loads(seq1, seq2, geo, bp0 + 2, r0s[2], c0s[2], tid, stg);
    sweep(reinterpret_cast<const char*>(sh[1]), off0, strb, valid, o1, tid);
    write_lds(sh[0], stg, loff, tid);
    __syncthreads();

    // t=2: prefetch 3, sweep 2 (sh[0]), write 3 -> sh[1]
    issue_loads(seq1, seq2, geo, bp0 + 3, r0s[3], c0s[3], tid, stg);
    sweep(reinterpret_cast<const char*>(sh[0]), off0, strb, valid, o2, tid);
    write_lds(sh[1], stg, loff, tid);
    __syncthreads();

    // t=3: sweep 3 (sh[1])
    sweep(reinterpret_cast<const char*>(sh[1]), off0, strb, valid, o3, tid);
}

extern "C" void kernel_launch(void* const* d_in, const int* in_sizes, int n_in,
                              void* d_out, int out_size, void* d_ws, size_t ws_size,
                              hipStream_t stream) {
    const float* seq1    = (const float*)d_in[0];
    const float* seq2    = (const float*)d_in[1];
    const float* geo     = (const float*)d_in[2];
    const int*   patches = (const int*)d_in[3];
    float*       out     = (float*)d_out;

    make_blocks_38860864094557_kernel<<<NBLK, NT, 0, stream>>>(seq1, seq2, geo, patches, out);
}